// Round 2
// baseline (810.772 us; speedup 1.0000x reference)
//
#include <hip/hip_runtime.h>
#include <stdint.h>

#define T_STEPS 500
#define NBATCH  128
#define NIN     784
#define KPAD    800
#define NH      1024
#define NSL     102
#define DECAY   0.8807970779778823f
#define MROWS   64000

typedef __attribute__((ext_vector_type(8))) short short8;
typedef __attribute__((ext_vector_type(4))) float f32x4;
typedef unsigned int u32;

static __device__ __forceinline__ unsigned short f2bf(float f) {
  union { float f; u32 u; } v; v.f = f;
  u32 r = (v.u + 0x7FFFu + ((v.u >> 16) & 1u)) >> 16;
  return (unsigned short)r;
}
static __device__ __forceinline__ float bf2f(unsigned short s) {
  union { u32 u; float f; } v; v.u = ((u32)s) << 16;
  return v.f;
}
static __device__ __forceinline__ u32 fu(float f) {
  union { float f; u32 u; } v; v.f = f; return v.u;
}
// async global->LDS, 16B per lane; LDS dst = wave-uniform base + lane*16
static __device__ __forceinline__ void gl16(const void* g, void* l) {
  __builtin_amdgcn_global_load_lds((const __attribute__((address_space(1))) u32*)g,
                                   (__attribute__((address_space(3))) u32*)l, 16, 0, 0);
}

// ---- prep: tiled transpose fc1[784][1024] -> fc1T[1024][800] bf16 (K pad 0) ----
__global__ __launch_bounds__(256) void prep_kernel(
    const float* __restrict__ fc1, unsigned short* __restrict__ fc1T,
    float* __restrict__ out_last) {
  __shared__ float tile[32][33];
  const int kb = blockIdx.x * 32, nb = blockIdx.y * 32;
  const int tx = threadIdx.x, ty = threadIdx.y;
#pragma unroll
  for (int i = 0; i < 4; ++i) {
    int k = kb + ty + i * 8, n = nb + tx;
    tile[ty + i * 8][tx] = (k < NIN) ? fc1[(size_t)k * NH + n] : 0.0f;
  }
  __syncthreads();
#pragma unroll
  for (int i = 0; i < 4; ++i) {
    int n = nb + ty + i * 8, k = kb + tx;
    fc1T[(size_t)n * KPAD + k] = f2bf(tile[tx][ty + i * 8]);
  }
  if (kb == 0 && nb == 0 && tx == 0 && ty == 0) *out_last = 500.0f;
}

// ---- GEMM: curq[64000][1024](bf16) = X[64000][784](fp32) @ fc1  -------------
// m97 structure: global_load_lds staging, A kept fp32 in LDS (XOR-swizzled
// 16B slots: phys = g ^ (row&7)), converted to bf16 at fragment read via
// v_perm_b32 truncation. B (fc1T, [n][k]) staged bf16, no swizzle needed
// (64B row stride already alternates bank quads).
__global__ __launch_bounds__(256) void gemm_kernel(
    const float* __restrict__ x, const unsigned short* __restrict__ fc1T,
    unsigned short* __restrict__ curq) {
  __shared__ __align__(16) float Af[128 * 32];           // 16 KB
  __shared__ __align__(16) unsigned short Bs[128 * 32];  // 8 KB

  const int tid = threadIdx.x;
  const int n0 = blockIdx.x * 128, m0 = blockIdx.y * 128;
  const int lane = tid & 63, wave = tid >> 6;
  const int wr = (wave >> 1) * 64, wc = (wave & 1) * 64;
  const int l16 = lane & 15, q = lane >> 4;

  // A staging map: lane -> row base+lane/8, phys slot lane&7, global slot g
  const int a_irow = lane >> 3;
  const int a_g = (lane & 7) ^ (a_irow & 7);
  const int a_col = a_g * 4;  // float col within 32-k tile
  // B staging map: lane -> row base+lane/4, col (lane&3)*8 bf16
  const int b_irow = lane >> 2;
  const int b_col = (lane & 3) * 8;

  f32x4 acc[4][4];
  const f32x4 z4 = {0.f, 0.f, 0.f, 0.f};
#pragma unroll
  for (int i = 0; i < 4; ++i)
#pragma unroll
    for (int j = 0; j < 4; ++j) acc[i][j] = z4;

  for (int k0 = 0; k0 < KPAD; k0 += 32) {
#pragma unroll
    for (int l = 0; l < 4; ++l) {
      const int rbase = wave * 32 + l * 8;
      // skip pad cols (k>=784): stale LDS there multiplies B=0 -> harmless,
      // and it also avoids any OOB read past x's end.
      if (k0 + a_col < NIN)
        gl16(x + (size_t)(m0 + rbase + a_irow) * NIN + k0 + a_col,
             &Af[rbase * 32]);
    }
#pragma unroll
    for (int l = 0; l < 2; ++l) {
      const int rbase = wave * 32 + l * 16;
      gl16(fc1T + (size_t)(n0 + rbase + b_irow) * KPAD + k0 + b_col,
           &Bs[rbase * 32]);
    }
    __syncthreads();

    short8 av[4], bv[4];
#pragma unroll
    for (int i = 0; i < 4; ++i) {
      const int r = wr + i * 16 + l16;
      const int s0 = (2 * q) ^ (l16 & 7);
      const float4 alo = *(const float4*)&Af[r * 32 + s0 * 4];
      const float4 ahi = *(const float4*)&Af[r * 32 + (s0 ^ 1) * 4];
      union { short8 s; u32 u[4]; } p;
      p.u[0] = __builtin_amdgcn_perm(fu(alo.y), fu(alo.x), 0x07060302u);
      p.u[1] = __builtin_amdgcn_perm(fu(alo.w), fu(alo.z), 0x07060302u);
      p.u[2] = __builtin_amdgcn_perm(fu(ahi.y), fu(ahi.x), 0x07060302u);
      p.u[3] = __builtin_amdgcn_perm(fu(ahi.w), fu(ahi.z), 0x07060302u);
      av[i] = p.s;
      bv[i] = *(const short8*)&Bs[(wc + i * 16 + l16) * 32 + q * 8];
    }
#pragma unroll
    for (int i = 0; i < 4; ++i)
#pragma unroll
      for (int j = 0; j < 4; ++j)
        acc[i][j] = __builtin_amdgcn_mfma_f32_16x16x32_bf16(av[i], bv[j],
                                                            acc[i][j], 0, 0, 0);
    __syncthreads();
  }

  // C/D layout (verified r1): col = lane&15, row = q*4 + reg
#pragma unroll
  for (int i = 0; i < 4; ++i)
#pragma unroll
    for (int j = 0; j < 4; ++j) {
      const int row = m0 + wr + i * 16 + q * 4;
      const int col = n0 + wc + j * 16 + l16;
#pragma unroll
      for (int rr = 0; rr < 4; ++rr)
        curq[(size_t)(row + rr) * NH + col] = f2bf(acc[i][j][rr]);
    }
}

// ---- scan: one block/batch; delta-spike incremental recurrent sums ---------
// Single barrier per step (3-buffer rotation), 4-step-ahead cv prefetch,
// speculative n==0 fast path so the cnt LDS latency overlaps the mem update.
__global__ __launch_bounds__(256) void scan_kernel(
    const unsigned short* __restrict__ curq, const float* __restrict__ wrec,
    float* __restrict__ out) {
  const int b = blockIdx.x, tid = threadIdx.x;
  const int h0 = tid * 4;

  __shared__ __align__(16) unsigned short lst[3][1024];
  __shared__ int cnt[3];

  const unsigned lane =
      __builtin_amdgcn_mbcnt_hi(~0u, __builtin_amdgcn_mbcnt_lo(~0u, 0u));
  const unsigned long long ltmask = (1ull << lane) - 1ull;

  float mem[4] = {0, 0, 0, 0}, rs[4] = {0, 0, 0, 0}, sp[4] = {0, 0, 0, 0};
  if (tid < 3) cnt[tid] = 0;
  __syncthreads();

  const size_t rowbase = (size_t)b * T_STEPS;

  ushort4 cv[2][4];
#pragma unroll
  for (int u = 0; u < 4; ++u)
    cv[0][u] = *(const ushort4*)&curq[(rowbase + u) * NH + h0];

  for (int tb = 0; tb < T_STEPS; tb += 4) {
    const int cb = (tb >> 2) & 1;
    if (tb + 4 < T_STEPS) {
#pragma unroll
      for (int u = 0; u < 4; ++u)
        cv[cb ^ 1][u] = *(const ushort4*)&curq[(rowbase + tb + 4 + u) * NH + h0];
    }
#pragma unroll
    for (int u = 0; u < 4; ++u) {
      const int t = tb + u;
      const int cur = t % 3, prv = (t + 2) % 3, nxt = (t + 1) % 3;
      const int n = cnt[prv];  // LDS read; latency overlapped by code below
      if (tid == 0) cnt[nxt] = 0;

      float cin[4] = {bf2f(cv[cb][u].x), bf2f(cv[cb][u].y),
                      bf2f(cv[cb][u].z), bf2f(cv[cb][u].w)};
      float nm[4], ns[4];
#pragma unroll
      for (int c = 0; c < 4; ++c) {  // speculative: assume no spike delta
        nm[c] = mem[c] * (DECAY * (1.0f - sp[c])) + (cin[c] + rs[c]);
        ns[c] = (nm[c] >= 1.0f) ? 1.0f : 0.0f;
      }
      if (__builtin_expect(n != 0, 0)) {
        int i = 0;
        for (; i + 8 <= n; i += 8) {  // batched: 8 loads in flight
          ushort4 ea = *(const ushort4*)&lst[prv][i];
          ushort4 eb = *(const ushort4*)&lst[prv][i + 4];
          const unsigned short es[8] = {ea.x, ea.y, ea.z, ea.w,
                                        eb.x, eb.y, eb.z, eb.w};
#pragma unroll
          for (int e = 0; e < 8; ++e) {
            const int j = es[e] & 1023;
            const float s = (es[e] & 0x8000u) ? 1.0f : -1.0f;
            const float4 w = *(const float4*)&wrec[(size_t)j * NH + h0];
            rs[0] += s * w.x; rs[1] += s * w.y;
            rs[2] += s * w.z; rs[3] += s * w.w;
          }
        }
        for (; i < n; ++i) {
          const unsigned e = lst[prv][i];
          const int j = e & 1023;
          const float s = (e & 0x8000u) ? 1.0f : -1.0f;
          const float4 w = *(const float4*)&wrec[(size_t)j * NH + h0];
          rs[0] += s * w.x; rs[1] += s * w.y;
          rs[2] += s * w.z; rs[3] += s * w.w;
        }
#pragma unroll
        for (int c = 0; c < 4; ++c) {  // redo with updated rs
          nm[c] = mem[c] * (DECAY * (1.0f - sp[c])) + (cin[c] + rs[c]);
          ns[c] = (nm[c] >= 1.0f) ? 1.0f : 0.0f;
        }
      }
#pragma unroll
      for (int c = 0; c < 4; ++c) mem[c] = nm[c];

      // out slice [:102]; rows are 408B so 8B-aligned stores only
      if (h0 + 4 <= NSL) {
        float2* o = (float2*)(out + (rowbase + t) * NSL + h0);
        o[0] = make_float2(ns[0], ns[1]);
        o[1] = make_float2(ns[2], ns[3]);
      } else if (h0 < NSL) {  // h0 == 100
        float2* o = (float2*)(out + (rowbase + t) * NSL + h0);
        o[0] = make_float2(ns[0], ns[1]);
      }

#pragma unroll
      for (int c = 0; c < 4; ++c) {
        const bool ch = (ns[c] != sp[c]);
        const unsigned long long msk = __ballot(ch);
        if (msk) {  // wave-uniform; skipped entirely in steady state
          int base = 0;
          if (lane == 0) base = atomicAdd(&cnt[cur], (int)__popcll(msk));
          base = __shfl(base, 0, 64);
          if (ch) {
            const int pos = base + (int)__popcll(msk & ltmask);
            lst[cur][pos] =
                (unsigned short)((h0 + c) | (ns[c] > 0.5f ? 0x8000u : 0u));
          }
        }
        sp[c] = ns[c];
      }
      __syncthreads();  // one barrier per step
    }
  }
}

extern "C" void kernel_launch(void* const* d_in, const int* in_sizes, int n_in,
                              void* d_out, int out_size, void* d_ws, size_t ws_size,
                              hipStream_t stream) {
  const float* x    = (const float*)d_in[0];  // [128][500][784] fp32
  const float* fc1  = (const float*)d_in[1];  // [784][1024] fp32
  const float* wrec = (const float*)d_in[2];  // [1024][1024] fp32
  float* out = (float*)d_out;                 // [128*500*102] + [1]

  unsigned short* fc1T = (unsigned short*)d_ws;                     // 1,638,400 B
  unsigned short* curq = (unsigned short*)((char*)d_ws + 1638400);  // 131,072,000 B

  prep_kernel<<<dim3(25, 32), dim3(32, 8), 0, stream>>>(fc1, fc1T,
                                                        out + (out_size - 1));
  gemm_kernel<<<dim3(8, 500), 256, 0, stream>>>(x, fc1T, curq);
  scan_kernel<<<dim3(NBATCH), 256, 0, stream>>>(curq, wrec, out);
}